// Round 1
// 319.421 us; speedup vs baseline: 1.0015x; 1.0015x over previous
//
#include <hip/hip_runtime.h>

// Problem constants (TextEncoder_55671366091616)
#define BB 32
#define SS 2048
#define DD 1024
#define EE 64
#define KK 8
#define TT 128            // N_TAGS
#define MM (BB * EE)      // 2048 output rows

#define KSPLIT 8
#define KCHUNK (DD / KSPLIT)   // 128
#define MT 32                  // M rows per block
#define LSTR 136               // LDS row stride in bf16 (272 B -> +4 banks/row)

typedef __attribute__((ext_vector_type(8))) short short8;   // bf16x8 frag
typedef __attribute__((ext_vector_type(4))) float f32x4;    // MFMA accumulator

__device__ __forceinline__ unsigned short f2bf(float f) {
    union { float f; unsigned int u; } v; v.f = f;
    unsigned int u = v.u + 0x7FFFu + ((v.u >> 16) & 1u);
    return (unsigned short)(u >> 16);
}

// ---------------------------------------------------------------------------
// out = bias broadcast. 256 blocks x 256 threads, one float4/thread.
// Must run before fc_fused_kernel (same stream): fused atomically adds into it.
// ---------------------------------------------------------------------------
__global__ __launch_bounds__(256) void bias_init_kernel(
    const float* __restrict__ fc_b,  // [T]
    float* __restrict__ out)         // [M*T]
{
    const int i = blockIdx.x * 256 + threadIdx.x;          // float4 index
    float4 b = *(const float4*)(fc_b + (i & 31) * 4);      // col = (4i) % 128
    *(float4*)(out + 4 * (size_t)i) = b;
}

// ---------------------------------------------------------------------------
// Fused gather+pool+GEMM, split-K=8, atomic epilogue into out.
// grid = (M/MT) * KSPLIT = 512 blocks, 256 threads (4 waves).
// Block (mt, ks): rows [mt*32, +32), K columns [ks*128, +128).
// Stage A (rewritten): gather loop fully unrolled to K=8 with clamped indices
//   (masked slots re-read idx[0]'s row -> L1 hit, zero weight). All row loads
//   are independent -> HBM latency overlaps instead of serializing per cnt.
// Stage B: W fp32 chunk [128 x 128] -> bf16 LDS (L2-resident across blocks).
// MFMA: 16x16x32 bf16; wave w: M-sub (w&1)*16, N-base (w>>1)*64.
// Epilogue: atomicAdd into out (bias pre-initialized) -> no workspace,
//   no reduce kernel, no 16 MB partial round-trip.
// ---------------------------------------------------------------------------
__global__ __launch_bounds__(256) void fc_fused_kernel(
    const float* __restrict__ hs,        // [B,S,D]
    const int*   __restrict__ subw_idx,  // [B,E,K]
    const int*   __restrict__ subw_cnt,  // [B,E]
    const int*   __restrict__ num_ent,   // [B]
    const float* __restrict__ fc_w,      // [T,D]
    float* __restrict__ out)             // [M,T] f32, pre-set to bias
{
    __shared__ unsigned short As[MT][LSTR];   // 8.5 KB
    __shared__ unsigned short Bs[TT][LSTR];   // 34 KB

    const int bx = blockIdx.x;
    const int mt = bx >> 3;              // 0..63
    const int ks = bx & (KSPLIT - 1);    // 0..7
    const int t  = threadIdx.x;
    const int wid  = t >> 6;
    const int lane = t & 63;
    const int k0 = ks * KCHUNK;

    // ---- Stage A: gather + mean-pool. 8 threads per row, 16 cols each. ----
    {
        const int r   = t >> 3;          // 0..31  entity row within tile
        const int sub = t & 7;           // 0..7   16-col slice
        const int be  = mt * MT + r;
        const int b   = be >> 6;
        const int e   = be & 63;
        const int cnt = subw_cnt[be];
        const int ne  = num_ent[b];
        const float scale = (e < ne) ? (1.0f / (float)cnt) : 0.0f;

        // All 8 index slots are allocated & hold valid [0,S) values.
        const int4* ip = (const int4*)(subw_idx + (size_t)be * KK);
        const int4 i0 = ip[0];
        const int4 i1 = ip[1];
        int idx[8] = { i0.x, i0.y, i0.z, i0.w, i1.x, i1.y, i1.z, i1.w };

        const float* base = hs + (size_t)b * SS * DD + k0 + sub * 16;

        float acc[16];
        #pragma unroll
        for (int j = 0; j < 16; ++j) acc[j] = 0.f;

        // Two batches of 4 rows: 4x4 float4 in flight per batch (~64 VGPRs),
        // loads within a batch fully independent.
        #pragma unroll
        for (int half = 0; half < 2; ++half) {
            float4 v[4][4];
            #pragma unroll
            for (int k = 0; k < 4; ++k) {
                const int kk = half * 4 + k;
                // masked slots re-read row idx[0] (L1 hit), weight 0 below
                const int s = (kk < cnt) ? idx[kk] : idx[0];
                const float4* p = (const float4*)(base + (size_t)s * DD);
                v[k][0] = p[0]; v[k][1] = p[1]; v[k][2] = p[2]; v[k][3] = p[3];
            }
            #pragma unroll
            for (int k = 0; k < 4; ++k) {
                const float w = ((half * 4 + k) < cnt) ? 1.0f : 0.0f;
                #pragma unroll
                for (int j = 0; j < 4; ++j) {
                    acc[4*j+0] = fmaf(w, v[k][j].x, acc[4*j+0]);
                    acc[4*j+1] = fmaf(w, v[k][j].y, acc[4*j+1]);
                    acc[4*j+2] = fmaf(w, v[k][j].z, acc[4*j+2]);
                    acc[4*j+3] = fmaf(w, v[k][j].w, acc[4*j+3]);
                }
            }
        }

        ushort4 o[4];
        #pragma unroll
        for (int j = 0; j < 4; ++j) {
            o[j].x = f2bf(acc[4*j+0] * scale);
            o[j].y = f2bf(acc[4*j+1] * scale);
            o[j].z = f2bf(acc[4*j+2] * scale);
            o[j].w = f2bf(acc[4*j+3] * scale);
        }
        *(ushort4*)&As[r][sub * 16 + 0]  = o[0];
        *(ushort4*)&As[r][sub * 16 + 4]  = o[1];
        *(ushort4*)&As[r][sub * 16 + 8]  = o[2];
        *(ushort4*)&As[r][sub * 16 + 12] = o[3];
    }

    // ---- Stage B: W fp32 -> bf16. 2 threads per tag row, 64 cols each. ----
    {
        const int n = t >> 1;            // 0..127 tag row
        const int h = (t & 1) * 64;      // col half
        const float4* wrow = (const float4*)(fc_w + (size_t)n * DD + k0 + h);
        #pragma unroll
        for (int j = 0; j < 16; ++j) {
            float4 v = wrow[j];
            ushort4 o;
            o.x = f2bf(v.x); o.y = f2bf(v.y); o.z = f2bf(v.z); o.w = f2bf(v.w);
            *(ushort4*)&Bs[n][h + j * 4] = o;
        }
    }
    __syncthreads();

    // ---- MFMA phase ----
    const int msub  = (wid & 1) * 16;
    const int nbase = (wid >> 1) * 64;
    const int lm = lane & 15;
    const int lq = (lane >> 4) * 8;

    f32x4 acc0 = {0.f,0.f,0.f,0.f}, acc1 = {0.f,0.f,0.f,0.f};
    f32x4 acc2 = {0.f,0.f,0.f,0.f}, acc3 = {0.f,0.f,0.f,0.f};

    #pragma unroll
    for (int kstep = 0; kstep < KCHUNK / 32; ++kstep) {
        const int kc = kstep * 32 + lq;
        short8 a  = *(const short8*)&As[msub + lm][kc];
        short8 b0 = *(const short8*)&Bs[nbase +  0 + lm][kc];
        short8 b1 = *(const short8*)&Bs[nbase + 16 + lm][kc];
        short8 b2 = *(const short8*)&Bs[nbase + 32 + lm][kc];
        short8 b3 = *(const short8*)&Bs[nbase + 48 + lm][kc];
        acc0 = __builtin_amdgcn_mfma_f32_16x16x32_bf16(a, b0, acc0, 0, 0, 0);
        acc1 = __builtin_amdgcn_mfma_f32_16x16x32_bf16(a, b1, acc1, 0, 0, 0);
        acc2 = __builtin_amdgcn_mfma_f32_16x16x32_bf16(a, b2, acc2, 0, 0, 0);
        acc3 = __builtin_amdgcn_mfma_f32_16x16x32_bf16(a, b3, acc3, 0, 0, 0);
    }

    // D layout: lane holds D[row=(lane>>4)*4 + r][col=lane&15]
    const int mrow = mt * MT + msub + (lane >> 4) * 4;
    const int ncol = nbase + (lane & 15);
    #pragma unroll
    for (int r = 0; r < 4; ++r) {
        const size_t base = (size_t)(mrow + r) * TT + ncol;
        atomicAdd(out + base +  0, acc0[r]);
        atomicAdd(out + base + 16, acc1[r]);
        atomicAdd(out + base + 32, acc2[r]);
        atomicAdd(out + base + 48, acc3[r]);
    }
}

extern "C" void kernel_launch(void* const* d_in, const int* in_sizes, int n_in,
                              void* d_out, int out_size, void* d_ws, size_t ws_size,
                              hipStream_t stream) {
    const float* hs       = (const float*)d_in[0];
    const int*   subw_idx = (const int*)  d_in[1];
    const int*   subw_cnt = (const int*)  d_in[2];
    const int*   num_ent  = (const int*)  d_in[3];
    const float* fc_w     = (const float*)d_in[4];
    const float* fc_b     = (const float*)d_in[5];
    float*       out      = (float*)d_out;

    bias_init_kernel<<<(MM * TT / 4) / 256, 256, 0, stream>>>(fc_b, out);
    fc_fused_kernel<<<(MM / MT) * KSPLIT, 256, 0, stream>>>(
        hs, subw_idx, subw_cnt, num_ent, fc_w, out);
}